// Round 1
// baseline (216.734 us; speedup 1.0000x reference)
//
#include <hip/hip_runtime.h>
#include <stdint.h>

#define NE    8
#define NTOK  1024
#define NH    1024
#define NI    1024
#define N13   2048

#define PREP_BLOCKS 513   // 1 routing + 512 X-convert
#define G1MAX       512   // sum_e ceil(cnt/256)*32 <= (2048/256 + 8)*32
#define G2MAX       256   // sum_e ceil(cnt/256)*16 <= (2048/256 + 8)*16

typedef __attribute__((ext_vector_type(8))) short short8;
typedef __attribute__((ext_vector_type(4))) float f32x4;
typedef unsigned short u16;
typedef unsigned int   u32;

__device__ __forceinline__ u16 f2bf(float x) {
    union { float f; u32 u; } v; v.f = x;
    return (u16)((v.u + 0x7fffu + ((v.u >> 16) & 1u)) >> 16);
}

__device__ __forceinline__ void async_ld16(u16* lds, const u16* g) {
    __builtin_amdgcn_global_load_lds(
        (const __attribute__((address_space(1))) u32*)g,
        (__attribute__((address_space(3))) u32*)lds, 16, 0, 0);
}

__device__ __forceinline__ bool find_tile(
    const int* __restrict__ counts, int tile, int bm, int ntn,
    int& e_o, int& mt_o, int& nt_o, int& cnt_o, int& base_o)
{
    int base = 0;
    #pragma unroll
    for (int e = 0; e < NE; e++) {
        const int cnt = counts[e];
        const int mtiles = (cnt + bm - 1) / bm;
        const int tiles = mtiles * ntn;
        if (tile < tiles) {
            e_o = e; mt_o = tile / ntn; nt_o = tile - (tile / ntn) * ntn;
            cnt_o = cnt; base_o = base; return true;
        }
        tile -= tiles; base += cnt;
    }
    return false;
}

// ===========================================================================
// Prep: block 0 = routing (+ inverse map for combine); blocks 1..512 = X->bf16
// No weight pass, no out zeroing.
// ===========================================================================
__global__ __launch_bounds__(256) void prep_kernel(
    const float* __restrict__ X, const float* __restrict__ logits,
    int* __restrict__ counts, int* __restrict__ pair_tok,
    int* __restrict__ inv, float* __restrict__ tokw,
    u16* __restrict__ Xb)
{
    __shared__ int s_cnt[NE];
    __shared__ int s_base[NE];
    const int tid = threadIdx.x;
    const int b = blockIdx.x;

    if (b == 0) {
        if (tid < NE) s_cnt[tid] = 0;
        __syncthreads();
        int eA[4][2]; int slotA[4][2]; float wA[4][2];
        #pragma unroll
        for (int i = 0; i < 4; i++) {
            const int t = tid * 4 + i;
            float l[NE];
            #pragma unroll
            for (int e = 0; e < NE; e++) l[e] = logits[t * NE + e];
            int i0 = 0;
            #pragma unroll
            for (int e = 1; e < NE; e++) if (l[e] > l[i0]) i0 = e;
            int i1 = -1;
            #pragma unroll
            for (int e = 0; e < NE; e++) {
                if (e == i0) continue;
                if (i1 < 0 || l[e] > l[i1]) i1 = e;
            }
            const float e10 = __expf(l[i1] - l[i0]);
            const float invw = 1.0f / (1.0f + e10);
            eA[i][0] = i0; eA[i][1] = i1;
            wA[i][0] = invw; wA[i][1] = e10 * invw;
            slotA[i][0] = atomicAdd(&s_cnt[i0], 1);
            slotA[i][1] = atomicAdd(&s_cnt[i1], 1);
        }
        __syncthreads();
        if (tid == 0) {
            int acc = 0;
            #pragma unroll
            for (int e = 0; e < NE; e++) { s_base[e] = acc; acc += s_cnt[e]; }
        }
        __syncthreads();
        if (tid < NE) counts[tid] = s_cnt[tid];
        #pragma unroll
        for (int i = 0; i < 4; i++) {
            const int t = tid * 4 + i;
            #pragma unroll
            for (int k = 0; k < 2; k++) {
                const int p = s_base[eA[i][k]] + slotA[i][k];
                pair_tok[p] = t;
                inv[t * 2 + k] = p;
                tokw[t * 2 + k] = wA[i][k];
            }
        }
    } else {
        const int i = (b - 1) * 256 + tid;
        const float4* s = (const float4*)X;
        const float4 a = s[2 * i], c = s[2 * i + 1];
        uint4 o;
        o.x = f2bf(a.x) | ((u32)f2bf(a.y) << 16);
        o.y = f2bf(a.z) | ((u32)f2bf(a.w) << 16);
        o.z = f2bf(c.x) | ((u32)f2bf(c.y) << 16);
        o.w = f2bf(c.z) | ((u32)f2bf(c.w) << 16);
        *(uint4*)(Xb + (size_t)i * 8) = o;
    }
}

// ===========================================================================
// GEMM1: act = silu(X.Wg)*X.Wu  — W13 fp32 read direct, converted in-register.
// BM=256 rows x 32 act cols (64 wcols), BK=32, 4 waves stacked in M.
// LDS B layout: element (n,k) at halfword n*32 + (k ^ ((n&3)<<3)).
// ===========================================================================
__global__ __launch_bounds__(256, 2) void gemm1_kernel(
    const u16* __restrict__ Xb, const float* __restrict__ W13,
    const int* __restrict__ counts, const int* __restrict__ pair_tok,
    u16* __restrict__ act)
{
    int e, mt, nt, cnt, base;
    if (!find_tile(counts, blockIdx.x, 256, NI / 32, e, mt, nt, cnt, base)) return;

    __shared__ u16 As[2][256 * 32];
    __shared__ u16 Bs[2][64 * 32];

    const int tid = threadIdx.x;
    const int ct  = nt * 32;

    // A gather: 4 rows/thread, XOR-swizzle applied on global side.
    const int m0 = tid >> 2;
    const int sw16 = (((tid & 3) ^ (m0 & 3)) << 3);
    const u16* ga[4];
    #pragma unroll
    for (int i = 0; i < 4; i++) {
        const int t = pair_tok[base + min(mt * 256 + i * 64 + m0, cnt - 1)];
        ga[i] = Xb + (size_t)t * NH + sw16;
    }

    // B source: thread covers k rows {2kp, 2kp+1} x cols {n0..n0+3}.
    const int kp  = tid & 15;
    const int ncg = tid >> 4;
    const int n0  = ncg << 2;
    const int f0  = (n0 < 32) ? (ct + n0) : (NI + ct + n0 - 32);
    const float* gw = W13 + ((size_t)e * NH + 2 * kp) * N13 + f0;

    const int lane = tid & 63, w = tid >> 6;
    const int quad = lane >> 4, lid = lane & 15;
    const int fsw = (quad ^ (lid & 3)) << 3;
    int aoff[4], boff[4];
    #pragma unroll
    for (int mi = 0; mi < 4; mi++)
        aoff[mi] = (w * 64 + mi * 16 + lid) * 32 + fsw;
    #pragma unroll
    for (int nf = 0; nf < 4; nf++)
        boff[nf] = (nf * 16 + lid) * 32 + fsw;

    f32x4 accg[4][2] = {};
    f32x4 accu[4][2] = {};

#define ISSUE1(b, k0)                                                 \
    { _Pragma("unroll") for (int i = 0; i < 4; i++)                   \
        async_ld16(&As[b][(tid + i * 256) * 8], ga[i] + (k0)); }

#define WR_B(b, v0, v1)                                                        \
    { _Pragma("unroll") for (int j = 0; j < 4; j++) {                          \
        const int n = n0 + j;                                                  \
        const u32 pv = (u32)f2bf(((const float*)&(v0))[j]) |                   \
                       ((u32)f2bf(((const float*)&(v1))[j]) << 16);            \
        *(u32*)&Bs[b][(n << 5) + ((2 * kp) ^ ((n & 3) << 3))] = pv;            \
    } }

#define COMP1(b)                                                               \
    {                                                                          \
        short8 av[4];                                                          \
        _Pragma("unroll") for (int mi = 0; mi < 4; mi++)                       \
            av[mi] = *(const short8*)&As[b][aoff[mi]];                         \
        short8 bv[4];                                                          \
        _Pragma("unroll") for (int nf = 0; nf < 4; nf++)                       \
            bv[nf] = *(const short8*)&Bs[b][boff[nf]];                         \
        _Pragma("unroll") for (int mi = 0; mi < 4; mi++) {                     \
            _Pragma("unroll") for (int c = 0; c < 2; c++) {                    \
                accg[mi][c] = __builtin_amdgcn_mfma_f32_16x16x32_bf16(         \
                    av[mi], bv[c], accg[mi][c], 0, 0, 0);                      \
                accu[mi][c] = __builtin_amdgcn_mfma_f32_16x16x32_bf16(         \
                    av[mi], bv[c + 2], accu[mi][c], 0, 0, 0);                  \
            }                                                                  \
        }                                                                      \
    }

    {
        const float4 v0 = *(const float4*)(gw);
        const float4 v1 = *(const float4*)(gw + N13);
        ISSUE1(0, 0);
        WR_B(0, v0, v1);
    }
    int buf = 0;
    for (int k0 = 32; k0 < NH; k0 += 32) {
        __syncthreads();
        const float4 v0 = *(const float4*)(gw + (size_t)k0 * N13);
        const float4 v1 = *(const float4*)(gw + (size_t)k0 * N13 + N13);
        ISSUE1(buf ^ 1, k0);
        COMP1(buf);
        WR_B(buf ^ 1, v0, v1);
        buf ^= 1;
    }
    __syncthreads();
    COMP1(buf);

    #pragma unroll
    for (int mi = 0; mi < 4; mi++) {
        #pragma unroll
        for (int r = 0; r < 4; r++) {
            const int row = mt * 256 + w * 64 + mi * 16 + quad * 4 + r;
            if (row < cnt) {
                #pragma unroll
                for (int c = 0; c < 2; c++) {
                    const float g = accg[mi][c][r], u = accu[mi][c][r];
                    const float s = g / (1.0f + __expf(-g)) * u;
                    act[(size_t)(base + row) * NI + ct + c * 16 + lid] = f2bf(s);
                }
            }
        }
    }
#undef ISSUE1
#undef WR_B
#undef COMP1
}

// ===========================================================================
// GEMM2: down[p] = act[p] . W2[e]  — W2 fp32 direct, fp32 output (no atomics).
// BM=256 x BN=64, BK=32, 4 waves stacked in M.
// ===========================================================================
__global__ __launch_bounds__(256, 2) void gemm2_kernel(
    const u16* __restrict__ act, const float* __restrict__ W2,
    const int* __restrict__ counts, float* __restrict__ down)
{
    int e, mt, nt, cnt, base;
    if (!find_tile(counts, blockIdx.x, 256, NH / 64, e, mt, nt, cnt, base)) return;

    __shared__ u16 As[2][256 * 32];
    __shared__ u16 Bs[2][64 * 32];

    const int tid = threadIdx.x;
    const int ct  = nt * 64;

    const int m0 = tid >> 2;
    const int sw16 = (((tid & 3) ^ (m0 & 3)) << 3);
    const u16* ga[4];
    #pragma unroll
    for (int i = 0; i < 4; i++) {
        const int p = base + min(mt * 256 + i * 64 + m0, cnt - 1);
        ga[i] = act + (size_t)p * NI + sw16;
    }

    const int kp  = tid & 15;
    const int ncg = tid >> 4;
    const int n0  = ncg << 2;
    const float* gw = W2 + ((size_t)e * NI + 2 * kp) * NH + ct + n0;

    const int lane = tid & 63, w = tid >> 6;
    const int quad = lane >> 4, lid = lane & 15;
    const int fsw = (quad ^ (lid & 3)) << 3;
    int aoff[4], boff[4];
    #pragma unroll
    for (int mi = 0; mi < 4; mi++)
        aoff[mi] = (w * 64 + mi * 16 + lid) * 32 + fsw;
    #pragma unroll
    for (int nj = 0; nj < 4; nj++)
        boff[nj] = (nj * 16 + lid) * 32 + fsw;

    f32x4 acc[4][4] = {};

#define ISSUE2(b, k0)                                                 \
    { _Pragma("unroll") for (int i = 0; i < 4; i++)                   \
        async_ld16(&As[b][(tid + i * 256) * 8], ga[i] + (k0)); }

#define WR_B2(b, v0, v1)                                                       \
    { _Pragma("unroll") for (int j = 0; j < 4; j++) {                          \
        const int n = n0 + j;                                                  \
        const u32 pv = (u32)f2bf(((const float*)&(v0))[j]) |                   \
                       ((u32)f2bf(((const float*)&(v1))[j]) << 16);            \
        *(u32*)&Bs[b][(n << 5) + ((2 * kp) ^ ((n & 3) << 3))] = pv;            \
    } }

#define COMP2(b)                                                               \
    {                                                                          \
        short8 av[4];                                                          \
        _Pragma("unroll") for (int mi = 0; mi < 4; mi++)                       \
            av[mi] = *(const short8*)&As[b][aoff[mi]];                         \
        short8 bv[4];                                                          \
        _Pragma("unroll") for (int nj = 0; nj < 4; nj++)                       \
            bv[nj] = *(const short8*)&Bs[b][boff[nj]];                         \
        _Pragma("unroll") for (int mi = 0; mi < 4; mi++)                       \
            _Pragma("unroll") for (int nj = 0; nj < 4; nj++)                   \
                acc[mi][nj] = __builtin_amdgcn_mfma_f32_16x16x32_bf16(         \
                    av[mi], bv[nj], acc[mi][nj], 0, 0, 0);                     \
    }

    {
        const float4 v0 = *(const float4*)(gw);
        const float4 v1 = *(const float4*)(gw + NH);
        ISSUE2(0, 0);
        WR_B2(0, v0, v1);
    }
    int buf = 0;
    for (int k0 = 32; k0 < NI; k0 += 32) {
        __syncthreads();
        const float4 v0 = *(const float4*)(gw + (size_t)k0 * NH);
        const float4 v1 = *(const float4*)(gw + (size_t)k0 * NH + NH);
        ISSUE2(buf ^ 1, k0);
        COMP2(buf);
        WR_B2(buf ^ 1, v0, v1);
        buf ^= 1;
    }
    __syncthreads();
    COMP2(buf);

    #pragma unroll
    for (int mi = 0; mi < 4; mi++) {
        #pragma unroll
        for (int r = 0; r < 4; r++) {
            const int row = mt * 256 + w * 64 + mi * 16 + quad * 4 + r;
            if (row < cnt) {
                #pragma unroll
                for (int nj = 0; nj < 4; nj++) {
                    down[(size_t)(base + row) * NH + ct + nj * 16 + lid] =
                        acc[mi][nj][r];
                }
            }
        }
    }
#undef ISSUE2
#undef WR_B2
#undef COMP2
}

// ===========================================================================
// Combine: out[t] = w0*down[p0] + w1*down[p1]  (replaces zero-init + atomics)
// ===========================================================================
__global__ __launch_bounds__(256) void combine_kernel(
    const float* __restrict__ down, const int* __restrict__ inv,
    const float* __restrict__ tokw, float* __restrict__ out)
{
    const int t = blockIdx.x;
    const int p0 = inv[2 * t], p1 = inv[2 * t + 1];
    const float w0 = tokw[2 * t], w1 = tokw[2 * t + 1];
    const int i = threadIdx.x * 4;
    const float4 a = *(const float4*)(down + (size_t)p0 * NH + i);
    const float4 b = *(const float4*)(down + (size_t)p1 * NH + i);
    float4 o;
    o.x = w0 * a.x + w1 * b.x;
    o.y = w0 * a.y + w1 * b.y;
    o.z = w0 * a.z + w1 * b.z;
    o.w = w0 * a.w + w1 * b.w;
    *(float4*)(out + (size_t)t * NH + i) = o;
}

// ===========================================================================
extern "C" void kernel_launch(void* const* d_in, const int* in_sizes, int n_in,
                              void* d_out, int out_size, void* d_ws, size_t ws_size,
                              hipStream_t stream)
{
    const float* X      = (const float*)d_in[0];
    const float* logits = (const float*)d_in[1];
    const float* W13    = (const float*)d_in[2];
    const float* W2     = (const float*)d_in[3];
    float* out = (float*)d_out;

    char* ws = (char*)d_ws;
    int*   counts   = (int*)(ws + 0);
    int*   pair_tok = (int*)(ws + 256);              // 8 KiB
    int*   inv      = (int*)(ws + 256 + 8192);       // 8 KiB
    float* tokw     = (float*)(ws + 256 + 16384);    // 8 KiB
    u16*   Xb       = (u16*)(ws + 65536);            // 2 MiB  [T][H] bf16
    u16*   act      = (u16*)(ws + (size_t)4 * 1024 * 1024);   // 4 MiB [P][I] bf16
    float* down     = (float*)(ws + (size_t)8 * 1024 * 1024); // 8 MiB [P][H] f32

    prep_kernel<<<PREP_BLOCKS, 256, 0, stream>>>(
        X, logits, counts, pair_tok, inv, tokw, Xb);
    gemm1_kernel<<<G1MAX, 256, 0, stream>>>(Xb, W13, counts, pair_tok, act);
    gemm2_kernel<<<G2MAX, 256, 0, stream>>>(act, W2, counts, down);
    combine_kernel<<<NTOK, 256, 0, stream>>>(down, inv, tokw, out);
}

// Round 2
// 186.801 us; speedup vs baseline: 1.1602x; 1.1602x over previous
//
#include <hip/hip_runtime.h>
#include <stdint.h>

#define NE    8
#define NTOK  1024
#define NH    1024
#define NI    1024
#define N13   2048

#define PREP_BLOCKS 513
#define G1MAX       768   // sum_e ceil(cnt/128) <= 24, * 32 ntiles
#define G2MAX       768   // sum_e ceil(cnt/128) <= 24, * 16 ntiles * 2 ksplit

typedef __attribute__((ext_vector_type(8))) short short8;
typedef __attribute__((ext_vector_type(4))) float f32x4;
typedef unsigned short u16;
typedef unsigned int   u32;

__device__ __forceinline__ u16 f2bf(float x) {
    union { float f; u32 u; } v; v.f = x;
    return (u16)((v.u + 0x7fffu + ((v.u >> 16) & 1u)) >> 16);
}

__device__ __forceinline__ u32 pack2(float a, float b) {
    return (u32)f2bf(a) | ((u32)f2bf(b) << 16);
}

__device__ __forceinline__ void async_ld16(u16* lds, const u16* g) {
    __builtin_amdgcn_global_load_lds(
        (const __attribute__((address_space(1))) u32*)g,
        (__attribute__((address_space(3))) u32*)lds, 16, 0, 0);
}

__device__ __forceinline__ bool find_tile(
    const int* __restrict__ counts, int tile, int bm, int ntn,
    int& e_o, int& mt_o, int& nt_o, int& cnt_o, int& base_o)
{
    int base = 0;
    #pragma unroll
    for (int e = 0; e < NE; e++) {
        const int cnt = counts[e];
        const int mtiles = (cnt + bm - 1) / bm;
        const int tiles = mtiles * ntn;
        if (tile < tiles) {
            e_o = e; mt_o = tile / ntn; nt_o = tile - (tile / ntn) * ntn;
            cnt_o = cnt; base_o = base; return true;
        }
        tile -= tiles; base += cnt;
    }
    return false;
}

// ===========================================================================
// Prep: block 0 = routing (+ inverse map); blocks 1..512 = X -> bf16.
// X stored LINEAR bf16 [T][H]; GEMM A-loads pre-swizzle on the global side.
// ===========================================================================
__global__ __launch_bounds__(256) void prep_kernel(
    const float* __restrict__ X, const float* __restrict__ logits,
    int* __restrict__ counts, int* __restrict__ pair_tok,
    int* __restrict__ inv, float* __restrict__ tokw,
    u16* __restrict__ Xb)
{
    __shared__ int s_cnt[NE];
    __shared__ int s_base[NE];
    const int tid = threadIdx.x;
    const int b = blockIdx.x;

    if (b == 0) {
        if (tid < NE) s_cnt[tid] = 0;
        __syncthreads();
        int eA[4][2]; int slotA[4][2]; float wA[4][2];
        #pragma unroll
        for (int i = 0; i < 4; i++) {
            const int t = tid * 4 + i;
            float l[NE];
            #pragma unroll
            for (int e = 0; e < NE; e++) l[e] = logits[t * NE + e];
            int i0 = 0;
            #pragma unroll
            for (int e = 1; e < NE; e++) if (l[e] > l[i0]) i0 = e;
            int i1 = -1;
            #pragma unroll
            for (int e = 0; e < NE; e++) {
                if (e == i0) continue;
                if (i1 < 0 || l[e] > l[i1]) i1 = e;
            }
            const float e10 = __expf(l[i1] - l[i0]);
            const float invw = 1.0f / (1.0f + e10);
            eA[i][0] = i0; eA[i][1] = i1;
            wA[i][0] = invw; wA[i][1] = e10 * invw;
            slotA[i][0] = atomicAdd(&s_cnt[i0], 1);
            slotA[i][1] = atomicAdd(&s_cnt[i1], 1);
        }
        __syncthreads();
        if (tid == 0) {
            int acc = 0;
            #pragma unroll
            for (int e = 0; e < NE; e++) { s_base[e] = acc; acc += s_cnt[e]; }
        }
        __syncthreads();
        if (tid < NE) counts[tid] = s_cnt[tid];
        #pragma unroll
        for (int i = 0; i < 4; i++) {
            const int t = tid * 4 + i;
            #pragma unroll
            for (int k = 0; k < 2; k++) {
                const int p = s_base[eA[i][k]] + slotA[i][k];
                pair_tok[p] = t;
                inv[t * 2 + k] = p;
                tokw[t * 2 + k] = wA[i][k];
            }
        }
    } else {
        const int i = (b - 1) * 256 + tid;
        const float4* s = (const float4*)X;
        const float4 a = s[2 * i], c = s[2 * i + 1];
        uint4 o;
        o.x = pack2(a.x, a.y);
        o.y = pack2(a.z, a.w);
        o.z = pack2(c.x, c.y);
        o.w = pack2(c.z, c.w);
        *(uint4*)(Xb + (size_t)i * 8) = o;
    }
}

// ===========================================================================
// GEMM1: act = silu(X.Wg)*X.Wu   BM=128 x 32 act cols (64 wcols), BK=32.
// W13 fp32 read COALESCED (n across lanes), cvt in-reg, ds_write swizzled.
// LDS element (r,k) at halfword r*32 + ((k>>3 ^ ((r>>2)&3))*8 + (k&7)).
// ===========================================================================
__global__ __launch_bounds__(256, 3) void gemm1_kernel(
    const u16* __restrict__ Xb, const float* __restrict__ W13,
    const int* __restrict__ counts, const int* __restrict__ pair_tok,
    u16* __restrict__ act)
{
    int e, mt, nt, cnt, base;
    if (!find_tile(counts, blockIdx.x, 128, NI / 32, e, mt, nt, cnt, base)) return;

    __shared__ u16 As[2][128 * 32];
    __shared__ u16 Bs[2][64 * 32];

    const int tid = threadIdx.x;
    const int ct  = nt * 32;

    // A: gload_lds, pre-swizzled global k-offset; s(m) = (m>>2)&3 = (tid>>4)&3
    const int m0 = tid >> 2;
    const int sw16 = (((tid & 3) ^ ((tid >> 4) & 3)) << 3);
    const int t0 = pair_tok[base + min(mt * 128 + m0, cnt - 1)];
    const int t1 = pair_tok[base + min(mt * 128 + 64 + m0, cnt - 1)];
    const u16* ga0 = Xb + (size_t)t0 * NH + sw16;
    const u16* ga1 = Xb + (size_t)t1 * NH + sw16;

    // B: coalesced fp32. n0 across lanes, k-pair across tid>>4.
    const int n0 = (tid & 15) << 2;
    const int kp = tid >> 4;
    const int f0 = (n0 < 32) ? (ct + n0) : (NI + ct + n0 - 32);
    const float* gw = W13 + ((size_t)e * NH + 2 * kp) * N13 + f0;
    // write base (halfwords): s(n) = (n>>2)&3 = tid&3 for all j
    const int bwr = (((kp >> 2) ^ (tid & 3)) << 3) + ((kp & 3) << 1);

    const int lane = tid & 63, w = tid >> 6;
    const int quad = lane >> 4, lid = lane & 15;
    const int rw = w >> 1, cw = w & 1;
    const int fsw = ((quad ^ ((lid >> 2) & 3)) << 3);
    int aoff[4];
    #pragma unroll
    for (int mi = 0; mi < 4; mi++)
        aoff[mi] = (rw * 64 + mi * 16 + lid) * 32 + fsw;
    const int bgoff = (cw * 16 + lid) * 32 + fsw;
    const int buoff = (32 + cw * 16 + lid) * 32 + fsw;

    f32x4 accg[4] = {};
    f32x4 accu[4] = {};

#define ISSUE1(b, k0)                                        \
    {                                                        \
        async_ld16(&As[b][tid * 8],         ga0 + (k0));     \
        async_ld16(&As[b][(tid + 256) * 8], ga1 + (k0));     \
    }
#define LOADB1(P0, P1, k0)                                            \
    {                                                                 \
        P0 = *(const float4*)(gw + (size_t)(k0) * N13);               \
        P1 = *(const float4*)(gw + (size_t)(k0) * N13 + N13);         \
    }
#define WRB1(b, P0, P1)                                               \
    {                                                                 \
        u32* d = (u32*)&Bs[b][(n0 << 5) + bwr];                       \
        d[0]  = pack2(P0.x, P1.x);                                    \
        d[16] = pack2(P0.y, P1.y);                                    \
        d[32] = pack2(P0.z, P1.z);                                    \
        d[48] = pack2(P0.w, P1.w);                                    \
    }
#define COMP1(b)                                                               \
    {                                                                          \
        short8 av[4];                                                          \
        _Pragma("unroll") for (int mi = 0; mi < 4; mi++)                       \
            av[mi] = *(const short8*)&As[b][aoff[mi]];                         \
        const short8 gv = *(const short8*)&Bs[b][bgoff];                       \
        const short8 uv = *(const short8*)&Bs[b][buoff];                       \
        _Pragma("unroll") for (int mi = 0; mi < 4; mi++) {                     \
            accg[mi] = __builtin_amdgcn_mfma_f32_16x16x32_bf16(                \
                av[mi], gv, accg[mi], 0, 0, 0);                                \
            accu[mi] = __builtin_amdgcn_mfma_f32_16x16x32_bf16(                \
                av[mi], uv, accu[mi], 0, 0, 0);                                \
        }                                                                      \
    }

    float4 p0, p1, q0, q1;
    LOADB1(q0, q1, 0);
    ISSUE1(0, 0);
    WRB1(0, q0, q1);
    LOADB1(q0, q1, 32);
    int buf = 0;
    for (int k0 = 32; k0 < NH; k0 += 32) {
        __syncthreads();
        if (k0 + 32 < NH) LOADB1(p0, p1, k0 + 32);
        ISSUE1(buf ^ 1, k0);
        COMP1(buf);
        WRB1(buf ^ 1, q0, q1);
        q0 = p0; q1 = p1;
        buf ^= 1;
    }
    __syncthreads();
    COMP1(buf);

    const int col = ct + cw * 16 + lid;
    #pragma unroll
    for (int mi = 0; mi < 4; mi++) {
        #pragma unroll
        for (int r = 0; r < 4; r++) {
            const int row = mt * 128 + rw * 64 + mi * 16 + quad * 4 + r;
            if (row < cnt) {
                const float g = accg[mi][r], u = accu[mi][r];
                const float s = g / (1.0f + __expf(-g)) * u;
                act[(size_t)(base + row) * NI + col] = f2bf(s);
            }
        }
    }
#undef ISSUE1
#undef LOADB1
#undef WRB1
#undef COMP1
}

// ===========================================================================
// GEMM2: down[kh][p] = act[p][kh-half] . W2[e][kh-half]   BM=128 x BN=64,
// K-split 2 (no atomics). W2 fp32 coalesced, cvt in-reg.
// ===========================================================================
__global__ __launch_bounds__(256, 3) void gemm2_kernel(
    const u16* __restrict__ act, const float* __restrict__ W2,
    const int* __restrict__ counts,
    float* __restrict__ down0, float* __restrict__ down1)
{
    int e, mt, ntq, cnt, base;
    if (!find_tile(counts, blockIdx.x, 128, (NH / 64) * 2, e, mt, ntq, cnt, base)) return;
    const int kh = ntq & 1;
    const int nt = ntq >> 1;
    const int ct = nt * 64;
    const int kbase = kh * 512;
    float* __restrict__ dwn = kh ? down1 : down0;

    __shared__ u16 As[2][128 * 32];
    __shared__ u16 Bs[2][64 * 32];

    const int tid = threadIdx.x;

    const int m0 = tid >> 2;
    const int sw16 = (((tid & 3) ^ ((tid >> 4) & 3)) << 3);
    const int p0r = base + min(mt * 128 + m0, cnt - 1);
    const int p1r = base + min(mt * 128 + 64 + m0, cnt - 1);
    const u16* ga0 = act + (size_t)p0r * NI + kbase + sw16;
    const u16* ga1 = act + (size_t)p1r * NI + kbase + sw16;

    const int n0 = (tid & 15) << 2;
    const int kp = tid >> 4;
    const float* gw = W2 + ((size_t)e * NI + kbase + 2 * kp) * NH + ct + n0;
    const int bwr = (((kp >> 2) ^ (tid & 3)) << 3) + ((kp & 3) << 1);

    const int lane = tid & 63, w = tid >> 6;
    const int quad = lane >> 4, lid = lane & 15;
    const int rw = w >> 1, cw = w & 1;
    const int fsw = ((quad ^ ((lid >> 2) & 3)) << 3);
    int aoff[4], boff[2];
    #pragma unroll
    for (int mi = 0; mi < 4; mi++)
        aoff[mi] = (rw * 64 + mi * 16 + lid) * 32 + fsw;
    #pragma unroll
    for (int nj = 0; nj < 2; nj++)
        boff[nj] = (cw * 32 + nj * 16 + lid) * 32 + fsw;

    f32x4 acc[4][2] = {};

#define ISSUE2(b, k0)                                        \
    {                                                        \
        async_ld16(&As[b][tid * 8],         ga0 + (k0));     \
        async_ld16(&As[b][(tid + 256) * 8], ga1 + (k0));     \
    }
#define LOADB2(P0, P1, k0)                                            \
    {                                                                 \
        P0 = *(const float4*)(gw + (size_t)(k0) * NH);                \
        P1 = *(const float4*)(gw + (size_t)(k0) * NH + NH);           \
    }
#define WRB2(b, P0, P1)                                               \
    {                                                                 \
        u32* d = (u32*)&Bs[b][(n0 << 5) + bwr];                       \
        d[0]  = pack2(P0.x, P1.x);                                    \
        d[16] = pack2(P0.y, P1.y);                                    \
        d[32] = pack2(P0.z, P1.z);                                    \
        d[48] = pack2(P0.w, P1.w);                                    \
    }
#define COMP2(b)                                                               \
    {                                                                          \
        short8 av[4], bv[2];                                                   \
        _Pragma("unroll") for (int mi = 0; mi < 4; mi++)                       \
            av[mi] = *(const short8*)&As[b][aoff[mi]];                         \
        _Pragma("unroll") for (int nj = 0; nj < 2; nj++)                       \
            bv[nj] = *(const short8*)&Bs[b][boff[nj]];                         \
        _Pragma("unroll") for (int mi = 0; mi < 4; mi++)                       \
            _Pragma("unroll") for (int nj = 0; nj < 2; nj++)                   \
                acc[mi][nj] = __builtin_amdgcn_mfma_f32_16x16x32_bf16(         \
                    av[mi], bv[nj], acc[mi][nj], 0, 0, 0);                     \
    }

    float4 p0, p1, q0, q1;
    LOADB2(q0, q1, 0);
    ISSUE2(0, 0);
    WRB2(0, q0, q1);
    LOADB2(q0, q1, 32);
    int buf = 0;
    for (int k0 = 32; k0 < 512; k0 += 32) {
        __syncthreads();
        if (k0 + 32 < 512) LOADB2(p0, p1, k0 + 32);
        ISSUE2(buf ^ 1, k0);
        COMP2(buf);
        WRB2(buf ^ 1, q0, q1);
        q0 = p0; q1 = p1;
        buf ^= 1;
    }
    __syncthreads();
    COMP2(buf);

    #pragma unroll
    for (int mi = 0; mi < 4; mi++) {
        #pragma unroll
        for (int r = 0; r < 4; r++) {
            const int row = mt * 128 + rw * 64 + mi * 16 + quad * 4 + r;
            if (row < cnt) {
                #pragma unroll
                for (int nj = 0; nj < 2; nj++) {
                    dwn[(size_t)(base + row) * NH + ct + cw * 32 + nj * 16 + lid] =
                        acc[mi][nj][r];
                }
            }
        }
    }
#undef ISSUE2
#undef LOADB2
#undef WRB2
#undef COMP2
}

// ===========================================================================
// Combine: out[t] = w0*(d0[p0]+d1[p0]) + w1*(d0[p1]+d1[p1])
// ===========================================================================
__global__ __launch_bounds__(256) void combine_kernel(
    const float* __restrict__ down0, const float* __restrict__ down1,
    const int* __restrict__ inv, const float* __restrict__ tokw,
    float* __restrict__ out)
{
    const int t = blockIdx.x;
    const int p0 = inv[2 * t], p1 = inv[2 * t + 1];
    const float w0 = tokw[2 * t], w1 = tokw[2 * t + 1];
    const int i = threadIdx.x * 4;
    const float4 a0 = *(const float4*)(down0 + (size_t)p0 * NH + i);
    const float4 a1 = *(const float4*)(down1 + (size_t)p0 * NH + i);
    const float4 b0 = *(const float4*)(down0 + (size_t)p1 * NH + i);
    const float4 b1 = *(const float4*)(down1 + (size_t)p1 * NH + i);
    float4 o;
    o.x = w0 * (a0.x + a1.x) + w1 * (b0.x + b1.x);
    o.y = w0 * (a0.y + a1.y) + w1 * (b0.y + b1.y);
    o.z = w0 * (a0.z + a1.z) + w1 * (b0.z + b1.z);
    o.w = w0 * (a0.w + a1.w) + w1 * (b0.w + b1.w);
    *(float4*)(out + (size_t)t * NH + i) = o;
}

// ===========================================================================
extern "C" void kernel_launch(void* const* d_in, const int* in_sizes, int n_in,
                              void* d_out, int out_size, void* d_ws, size_t ws_size,
                              hipStream_t stream)
{
    const float* X      = (const float*)d_in[0];
    const float* logits = (const float*)d_in[1];
    const float* W13    = (const float*)d_in[2];
    const float* W2     = (const float*)d_in[3];
    float* out = (float*)d_out;

    char* ws = (char*)d_ws;
    int*   counts   = (int*)(ws + 0);
    int*   pair_tok = (int*)(ws + 1024);             // 8 KiB
    int*   inv      = (int*)(ws + 16384);            // 8 KiB
    float* tokw     = (float*)(ws + 32768);          // 8 KiB
    u16*   Xb       = (u16*)(ws + 65536);            // 2 MiB  [T][H] bf16
    u16*   act      = (u16*)(ws + (size_t)4  * 1024 * 1024);  // 4 MiB [P][I] bf16
    float* down0    = (float*)(ws + (size_t)8  * 1024 * 1024); // 8 MiB [P][H] f32
    float* down1    = (float*)(ws + (size_t)16 * 1024 * 1024); // 8 MiB [P][H] f32

    prep_kernel<<<PREP_BLOCKS, 256, 0, stream>>>(
        X, logits, counts, pair_tok, inv, tokw, Xb);
    gemm1_kernel<<<G1MAX, 256, 0, stream>>>(Xb, W13, counts, pair_tok, act);
    gemm2_kernel<<<G2MAX, 256, 0, stream>>>(act, W2, counts, down0, down1);
    combine_kernel<<<NTOK, 256, 0, stream>>>(down0, down1, inv, tokw, out);
}

// Round 3
// 178.454 us; speedup vs baseline: 1.2145x; 1.0468x over previous
//
#include <hip/hip_runtime.h>
#include <stdint.h>

#define NE    8
#define NTOK  1024
#define NH    1024
#define NI    1024
#define N13   2048

#define PREP_BLOCKS 513
#define G1MAX       768
#define G2MAX       768

typedef __attribute__((ext_vector_type(8))) short short8;
typedef __attribute__((ext_vector_type(4))) float f32x4;
typedef unsigned short u16;
typedef unsigned int   u32;

__device__ __forceinline__ u16 f2bf(float x) {
    union { float f; u32 u; } v; v.f = x;
    return (u16)((v.u + 0x7fffu + ((v.u >> 16) & 1u)) >> 16);
}
__device__ __forceinline__ u32 pack2(float a, float b) {
    return (u32)f2bf(a) | ((u32)f2bf(b) << 16);
}
__device__ __forceinline__ void async_ld16(u16* lds, const u16* g) {
    __builtin_amdgcn_global_load_lds(
        (const __attribute__((address_space(1))) u32*)g,
        (__attribute__((address_space(3))) u32*)lds, 16, 0, 0);
}

// mt-innermost: adjacent blocks share the same weight panel (L2/L3 reuse)
__device__ __forceinline__ bool find_tile_mt(
    const int* __restrict__ counts, int tile, int bm, int ntn,
    int& e_o, int& mt_o, int& nt_o, int& cnt_o, int& base_o)
{
    int base = 0;
    #pragma unroll
    for (int e = 0; e < NE; e++) {
        const int cnt = counts[e];
        const int mtiles = (cnt + bm - 1) / bm;
        const int tiles = mtiles * ntn;
        if (tile < tiles) {
            e_o = e; mt_o = tile % mtiles; nt_o = tile / mtiles;
            cnt_o = cnt; base_o = base; return true;
        }
        tile -= tiles; base += cnt;
    }
    return false;
}

// counted-vmcnt sync: leave newest N vmem ops in flight across the barrier
#define SYNC(N)                                                            \
    asm volatile("s_waitcnt vmcnt(" #N ") lgkmcnt(0)" ::: "memory");       \
    __builtin_amdgcn_s_barrier();                                          \
    __builtin_amdgcn_sched_barrier(0);

// ===========================================================================
// Prep: block 0 = routing (+ inverse map); blocks 1..512 = X -> bf16 (linear)
// ===========================================================================
__global__ __launch_bounds__(256) void prep_kernel(
    const float* __restrict__ X, const float* __restrict__ logits,
    int* __restrict__ counts, int* __restrict__ pair_tok,
    int* __restrict__ inv, float* __restrict__ tokw,
    u16* __restrict__ Xb)
{
    __shared__ int s_cnt[NE];
    __shared__ int s_base[NE];
    const int tid = threadIdx.x;
    const int b = blockIdx.x;

    if (b == 0) {
        if (tid < NE) s_cnt[tid] = 0;
        __syncthreads();
        int eA[4][2]; int slotA[4][2]; float wA[4][2];
        #pragma unroll
        for (int i = 0; i < 4; i++) {
            const int t = tid * 4 + i;
            float l[NE];
            #pragma unroll
            for (int e = 0; e < NE; e++) l[e] = logits[t * NE + e];
            int i0 = 0;
            #pragma unroll
            for (int e = 1; e < NE; e++) if (l[e] > l[i0]) i0 = e;
            int i1 = -1;
            #pragma unroll
            for (int e = 0; e < NE; e++) {
                if (e == i0) continue;
                if (i1 < 0 || l[e] > l[i1]) i1 = e;
            }
            const float e10 = __expf(l[i1] - l[i0]);
            const float invw = 1.0f / (1.0f + e10);
            eA[i][0] = i0; eA[i][1] = i1;
            wA[i][0] = invw; wA[i][1] = e10 * invw;
            slotA[i][0] = atomicAdd(&s_cnt[i0], 1);
            slotA[i][1] = atomicAdd(&s_cnt[i1], 1);
        }
        __syncthreads();
        if (tid == 0) {
            int acc = 0;
            #pragma unroll
            for (int e = 0; e < NE; e++) { s_base[e] = acc; acc += s_cnt[e]; }
        }
        __syncthreads();
        if (tid < NE) counts[tid] = s_cnt[tid];
        #pragma unroll
        for (int i = 0; i < 4; i++) {
            const int t = tid * 4 + i;
            #pragma unroll
            for (int k = 0; k < 2; k++) {
                const int p = s_base[eA[i][k]] + slotA[i][k];
                pair_tok[p] = t;
                inv[t * 2 + k] = p;
                tokw[t * 2 + k] = wA[i][k];
            }
        }
    } else {
        const int i = (b - 1) * 256 + tid;
        const float4* s = (const float4*)X;
        const float4 a = s[2 * i], c = s[2 * i + 1];
        uint4 o;
        o.x = pack2(a.x, a.y);
        o.y = pack2(a.z, a.w);
        o.z = pack2(c.x, c.y);
        o.w = pack2(c.z, c.w);
        *(uint4*)(Xb + (size_t)i * 8) = o;
    }
}

// ===========================================================================
// GEMM1: act = silu(X.Wg)*X.Wu   BM=128, 32 act cols (64 wcols), BK=64.
// A via global_load_lds (3-bit XOR swizzle). B fp32 coalesced -> reg -> bf16
// ds_write (swizzle s(n)=(n^(n>>2))&7, conflict-free both sides).
// One raw barrier per K-step; counted vmcnt keeps 8 vmem in flight.
// ===========================================================================
__global__ __launch_bounds__(256, 3) void gemm1_kernel(
    const u16* __restrict__ Xb, const float* __restrict__ W13,
    const int* __restrict__ counts, const int* __restrict__ pair_tok,
    u16* __restrict__ act)
{
    int e, mt, nt, cnt, base;
    if (!find_tile_mt(counts, blockIdx.x, 128, NI / 32, e, mt, nt, cnt, base)) return;

    __shared__ __align__(16) u16 As[2][128 * 64];
    __shared__ __align__(16) u16 Bs[2][64 * 64];

    const int tid = threadIdx.x;
    const int ct  = nt * 32;

    // A staging: 4 issues x 16B/thread; dest linear, source chunk pre-swizzled
    const int csrc = (((tid & 7) ^ ((tid >> 3) & 7)) << 3);  // u16 units
    const u16* ga[4];
    #pragma unroll
    for (int q = 0; q < 4; q++) {
        const int row = mt * 128 + q * 32 + (tid >> 3);
        const int t = pair_tok[base + min(row, cnt - 1)];
        ga[q] = Xb + (size_t)t * NH + csrc;
    }

    // B staging: coalesced fp32 loads (n across lanes), swizzled ds_write
    const int n0  = (tid & 15) << 2;
    const int kpL = tid >> 4;                    // k-pair 0..15 (+16 for high)
    const int f0  = (n0 < 32) ? (ct + n0) : (NI + ct + n0 - 32);
    const float* gw = W13 + ((size_t)e * NH + 2 * kpL) * N13 + f0;
    int wboffL[4], wboffH[4];
    #pragma unroll
    for (int i = 0; i < 4; i++) {
        const int n = n0 + i;
        const int s = (n ^ (n >> 2)) & 7;
        wboffL[i] = n * 64 + ((((kpL >> 2)       ^ s) << 3)) + ((kpL & 3) << 1);
        wboffH[i] = n * 64 + (((((kpL >> 2) + 4) ^ s) << 3)) + ((kpL & 3) << 1);
    }

    // fragment read offsets
    const int lane = tid & 63, w = tid >> 6;
    const int quad = lane >> 4, lid = lane & 15;
    const int rw = w >> 1, cw = w & 1;
    int aoff[2][4], bgoff[2], buoff[2];
    #pragma unroll
    for (int kk = 0; kk < 2; kk++) {
        #pragma unroll
        for (int mi = 0; mi < 4; mi++) {
            const int row = rw * 64 + mi * 16 + lid;
            aoff[kk][mi] = row * 64 + (((kk * 4 + quad) ^ (row & 7)) << 3);
        }
        const int ng = cw * 16 + lid;
        bgoff[kk] = ng * 64 + (((kk * 4 + quad) ^ ((ng ^ (ng >> 2)) & 7)) << 3);
        const int nu = 32 + cw * 16 + lid;
        buoff[kk] = nu * 64 + (((kk * 4 + quad) ^ ((nu ^ (nu >> 2)) & 7)) << 3);
    }

    f32x4 accg[4] = {};
    f32x4 accu[4] = {};

#define ISSUEA1(B, K)                                                      \
    { _Pragma("unroll") for (int q = 0; q < 4; q++)                        \
        async_ld16(&As[B][q * 2048 + tid * 8], ga[q] + (K)); }
#define LOADB1(V0, V1, V2, V3, K)                                          \
    {                                                                      \
        V0 = *(const float4*)(gw + (size_t)(K) * N13);                     \
        V1 = *(const float4*)(gw + (size_t)(K) * N13 + N13);               \
        V2 = *(const float4*)(gw + (size_t)((K) + 32) * N13);              \
        V3 = *(const float4*)(gw + (size_t)((K) + 32) * N13 + N13);        \
    }
#define WRB1(B, V0, V1, V2, V3)                                            \
    { _Pragma("unroll") for (int i = 0; i < 4; i++) {                      \
        *(u32*)&Bs[B][wboffL[i]] =                                         \
            pack2(((const float*)&V0)[i], ((const float*)&V1)[i]);         \
        *(u32*)&Bs[B][wboffH[i]] =                                         \
            pack2(((const float*)&V2)[i], ((const float*)&V3)[i]);         \
    } }
#define COMP1(B)                                                           \
    { _Pragma("unroll") for (int kk = 0; kk < 2; kk++) {                   \
        const short8 gv = *(const short8*)&Bs[B][bgoff[kk]];               \
        const short8 uv = *(const short8*)&Bs[B][buoff[kk]];               \
        _Pragma("unroll") for (int mi = 0; mi < 4; mi++) {                 \
            const short8 av = *(const short8*)&As[B][aoff[kk][mi]];        \
            accg[mi] = __builtin_amdgcn_mfma_f32_16x16x32_bf16(            \
                av, gv, accg[mi], 0, 0, 0);                                \
            accu[mi] = __builtin_amdgcn_mfma_f32_16x16x32_bf16(            \
                av, uv, accu[mi], 0, 0, 0);                                \
        } } }

    float4 a0, a1, a2, a3, b0, b1, b2, b3;
    // prologue: B(0)->sb (drained at WRB), A(0) issued, B(1)->sa stays in flight
    LOADB1(b0, b1, b2, b3, 0);
    ISSUEA1(0, 0);
    WRB1(0, b0, b1, b2, b3);
    LOADB1(a0, a1, a2, a3, 64);

    // bodies 0..13 (KS=16); each: 4 gload_lds + 4 B loads = 8 vmem
    #pragma unroll
    for (int j = 0; j < 14; j += 2) {
        SYNC(4);                               // A(j) done; B(j+1) in flight
        ISSUEA1(1, (j + 1) * 64);
        LOADB1(b0, b1, b2, b3, (j + 2) * 64);
        COMP1(0);
        WRB1(1, a0, a1, a2, a3);
        SYNC(4);
        ISSUEA1(0, (j + 2) * 64);
        LOADB1(a0, a1, a2, a3, (j + 3) * 64);
        COMP1(1);
        WRB1(0, b0, b1, b2, b3);
    }
    // body 14 (no more B loads)
    SYNC(4);
    ISSUEA1(1, 15 * 64);
    COMP1(0);
    WRB1(1, a0, a1, a2, a3);
    // tail body 15
    SYNC(0);
    COMP1(1);

    const int col = ct + cw * 16 + lid;
    #pragma unroll
    for (int mi = 0; mi < 4; mi++) {
        #pragma unroll
        for (int r = 0; r < 4; r++) {
            const int row = mt * 128 + rw * 64 + mi * 16 + quad * 4 + r;
            if (row < cnt) {
                const float g = accg[mi][r], u = accu[mi][r];
                act[(size_t)(base + row) * NI + col] =
                    f2bf(g / (1.0f + __expf(-g)) * u);
            }
        }
    }
#undef ISSUEA1
#undef LOADB1
#undef WRB1
#undef COMP1
}

// ===========================================================================
// GEMM2: down[kh][p] = act[p][half] . W2[e][half]   BM=128 x BN=64, BK=64,
// K-split 2, same counted-vmcnt pipeline.
// ===========================================================================
__global__ __launch_bounds__(256, 3) void gemm2_kernel(
    const u16* __restrict__ act, const float* __restrict__ W2,
    const int* __restrict__ counts,
    float* __restrict__ down0, float* __restrict__ down1)
{
    int e, mt, ntq, cnt, base;
    if (!find_tile_mt(counts, blockIdx.x, 128, 16 * 2, e, mt, ntq, cnt, base)) return;
    const int kh = ntq & 1;
    const int nt = ntq >> 1;
    const int ct = nt * 64;
    const int kbase = kh * 512;
    float* __restrict__ dwn = kh ? down1 : down0;

    __shared__ __align__(16) u16 As[2][128 * 64];
    __shared__ __align__(16) u16 Bs[2][64 * 64];

    const int tid = threadIdx.x;

    const int csrc = (((tid & 7) ^ ((tid >> 3) & 7)) << 3);
    const u16* ga[4];
    #pragma unroll
    for (int q = 0; q < 4; q++) {
        const int row = mt * 128 + q * 32 + (tid >> 3);
        const int p = base + min(row, cnt - 1);
        ga[q] = act + (size_t)p * NI + kbase + csrc;
    }

    const int n0  = (tid & 15) << 2;
    const int kpL = tid >> 4;
    const float* gw = W2 + ((size_t)e * NI + kbase + 2 * kpL) * NH + ct + n0;
    int wboffL[4], wboffH[4];
    #pragma unroll
    for (int i = 0; i < 4; i++) {
        const int n = n0 + i;
        const int s = (n ^ (n >> 2)) & 7;
        wboffL[i] = n * 64 + ((((kpL >> 2)       ^ s) << 3)) + ((kpL & 3) << 1);
        wboffH[i] = n * 64 + (((((kpL >> 2) + 4) ^ s) << 3)) + ((kpL & 3) << 1);
    }

    const int lane = tid & 63, w = tid >> 6;
    const int quad = lane >> 4, lid = lane & 15;
    const int rw = w >> 1, cw = w & 1;
    int aoff[2][4], boff[2][2];
    #pragma unroll
    for (int kk = 0; kk < 2; kk++) {
        #pragma unroll
        for (int mi = 0; mi < 4; mi++) {
            const int row = rw * 64 + mi * 16 + lid;
            aoff[kk][mi] = row * 64 + (((kk * 4 + quad) ^ (row & 7)) << 3);
        }
        #pragma unroll
        for (int nj = 0; nj < 2; nj++) {
            const int n = cw * 32 + nj * 16 + lid;
            boff[kk][nj] = n * 64 +
                (((kk * 4 + quad) ^ ((n ^ (n >> 2)) & 7)) << 3);
        }
    }

    f32x4 acc[4][2] = {};

#define ISSUEA2(B, K)                                                      \
    { _Pragma("unroll") for (int q = 0; q < 4; q++)                        \
        async_ld16(&As[B][q * 2048 + tid * 8], ga[q] + (K)); }
#define LOADB2(V0, V1, V2, V3, K)                                          \
    {                                                                      \
        V0 = *(const float4*)(gw + (size_t)(K) * NH);                      \
        V1 = *(const float4*)(gw + (size_t)(K) * NH + NH);                 \
        V2 = *(const float4*)(gw + (size_t)((K) + 32) * NH);               \
        V3 = *(const float4*)(gw + (size_t)((K) + 32) * NH + NH);          \
    }
#define WRB2(B, V0, V1, V2, V3)                                            \
    { _Pragma("unroll") for (int i = 0; i < 4; i++) {                      \
        *(u32*)&Bs[B][wboffL[i]] =                                         \
            pack2(((const float*)&V0)[i], ((const float*)&V1)[i]);         \
        *(u32*)&Bs[B][wboffH[i]] =                                         \
            pack2(((const float*)&V2)[i], ((const float*)&V3)[i]);         \
    } }
#define COMP2(B)                                                           \
    { _Pragma("unroll") for (int kk = 0; kk < 2; kk++) {                   \
        const short8 bv0 = *(const short8*)&Bs[B][boff[kk][0]];            \
        const short8 bv1 = *(const short8*)&Bs[B][boff[kk][1]];            \
        _Pragma("unroll") for (int mi = 0; mi < 4; mi++) {                 \
            const short8 av = *(const short8*)&As[B][aoff[kk][mi]];        \
            acc[mi][0] = __builtin_amdgcn_mfma_f32_16x16x32_bf16(          \
                av, bv0, acc[mi][0], 0, 0, 0);                             \
            acc[mi][1] = __builtin_amdgcn_mfma_f32_16x16x32_bf16(          \
                av, bv1, acc[mi][1], 0, 0, 0);                             \
        } } }

    float4 a0, a1, a2, a3, b0, b1, b2, b3;
    LOADB2(b0, b1, b2, b3, 0);
    ISSUEA2(0, 0);
    WRB2(0, b0, b1, b2, b3);
    LOADB2(a0, a1, a2, a3, 64);

    // bodies 0..5 (KS=8)
    #pragma unroll
    for (int j = 0; j < 6; j += 2) {
        SYNC(4);
        ISSUEA2(1, (j + 1) * 64);
        LOADB2(b0, b1, b2, b3, (j + 2) * 64);
        COMP2(0);
        WRB2(1, a0, a1, a2, a3);
        SYNC(4);
        ISSUEA2(0, (j + 2) * 64);
        LOADB2(a0, a1, a2, a3, (j + 3) * 64);
        COMP2(1);
        WRB2(0, b0, b1, b2, b3);
    }
    // body 6
    SYNC(4);
    ISSUEA2(1, 7 * 64);
    COMP2(0);
    WRB2(1, a0, a1, a2, a3);
    // tail body 7
    SYNC(0);
    COMP2(1);

    #pragma unroll
    for (int mi = 0; mi < 4; mi++) {
        #pragma unroll
        for (int r = 0; r < 4; r++) {
            const int row = mt * 128 + rw * 64 + mi * 16 + quad * 4 + r;
            if (row < cnt) {
                #pragma unroll
                for (int nj = 0; nj < 2; nj++) {
                    dwn[(size_t)(base + row) * NH + ct + cw * 32 + nj * 16 + lid] =
                        acc[mi][nj][r];
                }
            }
        }
    }
#undef ISSUEA2
#undef LOADB2
#undef WRB2
#undef COMP2
}

// ===========================================================================
// Combine: out[t] = w0*(d0[p0]+d1[p0]) + w1*(d0[p1]+d1[p1])
// ===========================================================================
__global__ __launch_bounds__(256) void combine_kernel(
    const float* __restrict__ down0, const float* __restrict__ down1,
    const int* __restrict__ inv, const float* __restrict__ tokw,
    float* __restrict__ out)
{
    const int t = blockIdx.x;
    const int p0 = inv[2 * t], p1 = inv[2 * t + 1];
    const float w0 = tokw[2 * t], w1 = tokw[2 * t + 1];
    const int i = threadIdx.x * 4;
    const float4 a0 = *(const float4*)(down0 + (size_t)p0 * NH + i);
    const float4 a1 = *(const float4*)(down1 + (size_t)p0 * NH + i);
    const float4 b0 = *(const float4*)(down0 + (size_t)p1 * NH + i);
    const float4 b1 = *(const float4*)(down1 + (size_t)p1 * NH + i);
    float4 o;
    o.x = w0 * (a0.x + a1.x) + w1 * (b0.x + b1.x);
    o.y = w0 * (a0.y + a1.y) + w1 * (b0.y + b1.y);
    o.z = w0 * (a0.z + a1.z) + w1 * (b0.z + b1.z);
    o.w = w0 * (a0.w + a1.w) + w1 * (b0.w + b1.w);
    *(float4*)(out + (size_t)t * NH + i) = o;
}

// ===========================================================================
extern "C" void kernel_launch(void* const* d_in, const int* in_sizes, int n_in,
                              void* d_out, int out_size, void* d_ws, size_t ws_size,
                              hipStream_t stream)
{
    const float* X      = (const float*)d_in[0];
    const float* logits = (const float*)d_in[1];
    const float* W13    = (const float*)d_in[2];
    const float* W2     = (const float*)d_in[3];
    float* out = (float*)d_out;

    char* ws = (char*)d_ws;
    int*   counts   = (int*)(ws + 0);
    int*   pair_tok = (int*)(ws + 1024);
    int*   inv      = (int*)(ws + 16384);
    float* tokw     = (float*)(ws + 32768);
    u16*   Xb       = (u16*)(ws + 65536);                      // 2 MiB [T][H] bf16
    u16*   act      = (u16*)(ws + (size_t)4  * 1024 * 1024);   // 4 MiB [P][I] bf16
    float* down0    = (float*)(ws + (size_t)8  * 1024 * 1024); // 8 MiB
    float* down1    = (float*)(ws + (size_t)16 * 1024 * 1024); // 8 MiB

    prep_kernel<<<PREP_BLOCKS, 256, 0, stream>>>(
        X, logits, counts, pair_tok, inv, tokw, Xb);
    gemm1_kernel<<<G1MAX, 256, 0, stream>>>(Xb, W13, counts, pair_tok, act);
    gemm2_kernel<<<G2MAX, 256, 0, stream>>>(act, W2, counts, down0, down1);
    combine_kernel<<<NTOK, 256, 0, stream>>>(down0, down1, inv, tokw, out);
}